// Round 3
// baseline (428.821 us; speedup 1.0000x reference)
//
#include <hip/hip_runtime.h>

typedef unsigned short u16;
typedef unsigned int u32;
typedef __attribute__((ext_vector_type(8))) short short8;
typedef __attribute__((ext_vector_type(4))) float f32x4;

__device__ __forceinline__ u16 f2bf(float f) {
    u32 u = __float_as_uint(f);
    return (u16)((u + 0x7FFFu + ((u >> 16) & 1u)) >> 16);
}

// component of a float4 by (compile-time-unrolled) index
#define COMP(f4, e) ((e) == 0 ? (f4).x : (e) == 1 ? (f4).y : (e) == 2 ? (f4).z : (f4).w)

// async global->LDS, 16B per lane. LDS dest is wave-uniform base (+lane*16 implicit).
__device__ __forceinline__ void gld16(const u16* g, u16* l) {
    __builtin_amdgcn_global_load_lds(
        (const __attribute__((address_space(1))) unsigned int*)(unsigned long long)(const void*)g,
        (__attribute__((address_space(3))) unsigned int*)(unsigned long long)(void*)l,
        16, 0, 0);
}

// ---------------------------------------------------------------------------
// Kernel 0a REWRITE: NCHW fp32 -> halo-padded NHWC bf16.
// One block = one image row x ALL 256 channels (grid 2048 = 32 n x 64 row).
//  - read: 16 independent float4 loads/thread (4x deeper MLP than before),
//    lanes 0..15 contiguous 256B segments, 4 ic-rows per wave instr.
//  - in-register 4x4 transpose -> bf16 pack -> b64 LDS write.
//  - write: COMPLETE 512B pixel records; each wave stores 1KB contiguous,
//    each block streams 32KB contiguous (vs 128B quarters before).
// LDS tile [64 px][264 u16] (528B row stride: 16B aligned, +16B pad).
// ---------------------------------------------------------------------------
__global__ __launch_bounds__(256) void nchw2nhwc_pad(const float* __restrict__ x,
                                                     u16* __restrict__ xp) {
    __shared__ __align__(16) u16 T[64][264];
    const int tid = threadIdx.x;
    const int b   = blockIdx.x;
    const int n   = b >> 6;          // image
    const int row = b & 63;          // image row
    const int g16 = tid >> 4;        // 16-channel slab 0..15
    const int pxq = tid & 15;        // pixel quad 0..15

    // ---- phase 1: load 16ch x 4px fp32 (16 x float4, all independent) ----
    const float* src = x + ((size_t)n * 256 + g16 * 16) * 4096 + row * 64 + pxq * 4;
    float4 v[4][4];
#pragma unroll
    for (int u = 0; u < 4; ++u)
#pragma unroll
        for (int i = 0; i < 4; ++i)
            v[u][i] = *(const float4*)(src + (size_t)(u * 4 + i) * 4096);

    // ---- reg 4x4 transpose + bf16 pack + LDS write (b64 per (u,e)) ----
#pragma unroll
    for (int u = 0; u < 4; ++u) {
        const int ic = g16 * 16 + u * 4;
#pragma unroll
        for (int e = 0; e < 4; ++e) {
            const int px = pxq * 4 + e;
            const u32 lo = ((u32)f2bf(COMP(v[u][1], e)) << 16) | f2bf(COMP(v[u][0], e));
            const u32 hi = ((u32)f2bf(COMP(v[u][3], e)) << 16) | f2bf(COMP(v[u][2], e));
            *(uint2*)&T[px][ic] = make_uint2(lo, hi);
        }
    }
    __syncthreads();

    // ---- phase 2: write complete pixel records, fully contiguous ----
    const int c = tid & 31, p0 = tid >> 5;
    u16* dstN = xp + ((size_t)n * 4356 + (size_t)(row + 1) * 66 + 1) * 256 + c * 8;
#pragma unroll
    for (int pp = 0; pp < 8; ++pp) {
        const int px = pp * 8 + p0;
        *(uint4*)(dstN + (size_t)px * 256) = *(const uint4*)&T[px][c * 8];
    }

    // ---- halo zeroing (full 256-ch records) ----
    u16* hrow = xp + ((size_t)n * 4356 + (size_t)(row + 1) * 66) * 256;
    if (tid < 64) {                                   // wp = 0 and wp = 65
        const int wp = (tid >> 5) ? 65 : 0;
        uint4 zz = {0u, 0u, 0u, 0u};
        *(uint4*)(hrow + (size_t)wp * 256 + (tid & 31) * 8) = zz;
    }
    if (row == 0) {                                   // top halo row hp = 0
        u16* tb = xp + (size_t)n * 4356 * 256;
        uint4 zz = {0u, 0u, 0u, 0u};
        for (int i = tid; i < 2112; i += 256) *(uint4*)(tb + (size_t)i * 8) = zz;
    }
    if (row == 63) {                                  // bottom halo row hp = 65
        u16* bb = xp + ((size_t)n * 4356 + 65 * 66) * 256;
        uint4 zz = {0u, 0u, 0u, 0u};
        for (int i = tid; i < 2112; i += 256) *(uint4*)(bb + (size_t)i * 8) = zz;
    }
}

// ---------------------------------------------------------------------------
// Kernel 0b: hypernet weight generation, LDS-resident (unchanged).
// ---------------------------------------------------------------------------
__global__ __launch_bounds__(256) void wgen(const float* __restrict__ z,
                                            const float* __restrict__ W1,
                                            const float* __restrict__ B1,
                                            const float* __restrict__ W2,
                                            const float* __restrict__ B2,
                                            u16* __restrict__ wb) {
    __shared__ float zl[64][65];     // [l][n]
    __shared__ float w1s[4096];      // [d][n] flat
    __shared__ float aS[64][65];     // [l][d]
    __shared__ float w2s[9216];      // [kk][d] flat

    const int tid = threadIdx.x;
    const int b   = blockIdx.x >> 2;    // b1 block 0..15
    const int lc  = blockIdx.x & 3;     // l-chunk 0..3
    const int l   = tid & 63;           // lane = local latent index
    const int g   = tid >> 6;           // wave 0..3

    const float* zg  = z  + (size_t)lc * 4096;
    const float* w1g = W1 + (size_t)b * 4096;
    const float* w2g = W2 + (size_t)b * 9216;
#pragma unroll
    for (int k = 0; k < 4; ++k) {
        const int i4 = tid + k * 256;
        const float4 v = *(const float4*)(zg + (size_t)i4 * 4);
        const int lr = i4 >> 4, nr = (i4 * 4) & 63;
        zl[lr][nr] = v.x; zl[lr][nr + 1] = v.y; zl[lr][nr + 2] = v.z; zl[lr][nr + 3] = v.w;
        *(float4*)(w1s + (size_t)i4 * 4) = *(const float4*)(w1g + (size_t)i4 * 4);
    }
#pragma unroll
    for (int k = 0; k < 9; ++k) {
        const int i4 = tid + k * 256;
        *(float4*)(w2s + (size_t)i4 * 4) = *(const float4*)(w2g + (size_t)i4 * 4);
    }
    __syncthreads();

    {
        float acc[16];
#pragma unroll
        for (int j = 0; j < 16; ++j) acc[j] = B1[b * 64 + g * 16 + j];
#pragma unroll
        for (int nb = 0; nb < 16; ++nb) {
            float zv0 = zl[l][nb * 4 + 0];
            float zv1 = zl[l][nb * 4 + 1];
            float zv2 = zl[l][nb * 4 + 2];
            float zv3 = zl[l][nb * 4 + 3];
#pragma unroll
            for (int j = 0; j < 16; ++j) {
                const float4 w = *(const float4*)(w1s + (g * 16 + j) * 64 + nb * 4);
                acc[j] += w.x * zv0 + w.y * zv1 + w.z * zv2 + w.w * zv3;
            }
        }
#pragma unroll
        for (int j = 0; j < 16; ++j) aS[l][g * 16 + j] = acc[j];
    }
    __syncthreads();

    float acc2[36];
#pragma unroll
    for (int t = 0; t < 36; ++t) acc2[t] = B2[b * 144 + g * 36 + t];
#pragma unroll
    for (int db = 0; db < 16; ++db) {
        float av0 = aS[l][db * 4 + 0];
        float av1 = aS[l][db * 4 + 1];
        float av2 = aS[l][db * 4 + 2];
        float av3 = aS[l][db * 4 + 3];
#pragma unroll
        for (int t = 0; t < 36; ++t) {
            const float4 w = *(const float4*)(w2s + (g * 36 + t) * 64 + db * 4);
            acc2[t] += w.x * av0 + w.y * av1 + w.z * av2 + w.w * av3;
        }
    }

    const int lg = lc * 64 + l;
    const int ob = lg >> 4, ib = lg & 15;
#pragma unroll
    for (int t = 0; t < 36; ++t) {
        const int b2 = 4 * g + t / 9;
        const int tap = t % 9;
        wb[(size_t)(ob * 16 + b2) * 2304 + tap * 256 + ib * 16 + b] = f2bf(acc2[t]);
    }
}

// ---------------------------------------------------------------------------
// Kernel 1: implicit-GEMM conv (unchanged).
// ---------------------------------------------------------------------------
__global__ __launch_bounds__(256) void conv_mfma(const u16* __restrict__ xp,
                                                 const u16* __restrict__ wb,
                                                 float* __restrict__ out) {
    __shared__ __align__(16) u16 As[2][128 * 32];
    __shared__ __align__(16) u16 Bs[2][128 * 32];

    const int tid = threadIdx.x;
    const int b0  = blockIdx.x;
    const int bid = (b0 & 7) * 256 + (b0 >> 3);
    const int mt = bid & 1;
    const int nt = bid >> 1;
    const int n = nt >> 5;
    const int pimg = (nt & 31) << 7;
    const int oc0 = mt << 7;

    const int lane = tid & 63;
    const int wave = tid >> 6;
    const int wm = (wave >> 1) & 1, wn = wave & 1;
    const int lr = lane & 15, lq = lane >> 4;
    const int sw = (lq ^ (lr & 3)) * 8;

    const int ls = lane >> 2;
    const int swst = ((lane & 3) ^ (ls & 3)) * 8;
    const int rr0 = wave * 32 + ls;
    const int rr1 = rr0 + 16;
    const u16* wbA0 = wb + (size_t)(oc0 + rr0) * 2304 + swst;
    const u16* wbA1 = wb + (size_t)(oc0 + rr1) * 2304 + swst;
    const int p0 = pimg + rr0, p1 = pimg + rr1;
    const int pb0 = ((p0 >> 6) + 1) * 66 + (p0 & 63) + 1;
    const int pb1 = ((p1 >> 6) + 1) * 66 + (p1 & 63) + 1;
    const u16* xpN = xp + (size_t)n * 4356 * 256 + swst;

    auto stage = [&](int bi, int kt) {
        const int tap = kt >> 3, icb = kt & 7;
        const int t3 = tap / 3;
        const int dh = t3 - 1, dw = tap - t3 * 3 - 1;
        const int ko = tap * 256 + icb * 32;
        const int bo = (dh * 66 + dw) * 256 + icb * 32;
        u16* ab = &As[bi][wave * 1024];
        u16* bb = &Bs[bi][wave * 1024];
        gld16(wbA0 + ko, ab);
        gld16(wbA1 + ko, ab + 512);
        gld16(xpN + (pb0 * 256 + bo), bb);
        gld16(xpN + (pb1 * 256 + bo), bb + 512);
    };

    f32x4 acc[4][4];
    const f32x4 z4 = {0.f, 0.f, 0.f, 0.f};
#pragma unroll
    for (int i = 0; i < 4; ++i)
#pragma unroll
        for (int j = 0; j < 4; ++j) acc[i][j] = z4;

    stage(0, 0);
#pragma unroll 2
    for (int kt = 0; kt < 72; ++kt) {
        const int cur = kt & 1;
        __syncthreads();
        if (kt < 71) stage(cur ^ 1, kt + 1);

        const u16* Ab = &As[cur][0];
        const u16* Bb = &Bs[cur][0];
        short8 af[4], bf[4];
#pragma unroll
        for (int i = 0; i < 4; ++i) {
            af[i] = *(const short8*)(Ab + (wm * 64 + i * 16 + lr) * 32 + sw);
            bf[i] = *(const short8*)(Bb + (wn * 64 + i * 16 + lr) * 32 + sw);
        }
#pragma unroll
        for (int i = 0; i < 4; ++i)
#pragma unroll
            for (int j = 0; j < 4; ++j)
                acc[i][j] = __builtin_amdgcn_mfma_f32_16x16x32_bf16(
                    af[i], bf[j], acc[i][j], 0, 0, 0);
    }

    const size_t outn = (size_t)n * 256 * 4096;
#pragma unroll
    for (int i = 0; i < 4; ++i) {
        const int ocb = oc0 + wm * 64 + i * 16 + lq * 4;
#pragma unroll
        for (int j = 0; j < 4; ++j) {
            const int po = pimg + wn * 64 + j * 16 + lr;
            float* op = out + outn + (size_t)ocb * 4096 + po;
#pragma unroll
            for (int r = 0; r < 4; ++r) op[(size_t)r * 4096] = acc[i][j][r];
        }
    }
}

extern "C" void kernel_launch(void* const* d_in, const int* in_sizes, int n_in,
                              void* d_out, int out_size, void* d_ws, size_t ws_size,
                              hipStream_t stream) {
    const float* x  = (const float*)d_in[0];
    const float* z  = (const float*)d_in[1];
    const float* W1 = (const float*)d_in[2];
    const float* B1 = (const float*)d_in[3];
    const float* W2 = (const float*)d_in[4];
    const float* B2 = (const float*)d_in[5];
    float* out = (float*)d_out;

    u16* xp = (u16*)d_ws;
    u16* wb = xp + (size_t)32 * 4356 * 256;
    const size_t need = ((size_t)32 * 4356 * 256 + (size_t)256 * 2304) * 2;
    if (ws_size < need) return;

    nchw2nhwc_pad<<<dim3(2048), dim3(256), 0, stream>>>(x, xp);
    wgen<<<dim3(64), dim3(256), 0, stream>>>(z, W1, B1, W2, B2, wb);
    conv_mfma<<<dim3(2048), dim3(256), 0, stream>>>(xp, wb, out);
}

// Round 4
// 392.707 us; speedup vs baseline: 1.0920x; 1.0920x over previous
//
#include <hip/hip_runtime.h>

typedef unsigned short u16;
typedef unsigned int u32;
typedef __attribute__((ext_vector_type(8))) short short8;
typedef __attribute__((ext_vector_type(4))) float f32x4;

__device__ __forceinline__ u16 f2bf(float f) {
    u32 u = __float_as_uint(f);
    return (u16)((u + 0x7FFFu + ((u >> 16) & 1u)) >> 16);
}

#define COMP(f4, e) ((e) == 0 ? (f4).x : (e) == 1 ? (f4).y : (e) == 2 ? (f4).z : (f4).w)

// async global->LDS, 16B per lane. LDS dest is wave-uniform base (+lane*16 implicit).
__device__ __forceinline__ void gld16(const u16* g, u16* l) {
    __builtin_amdgcn_global_load_lds(
        (const __attribute__((address_space(1))) unsigned int*)(unsigned long long)(const void*)g,
        (__attribute__((address_space(3))) unsigned int*)(unsigned long long)(void*)l,
        16, 0, 0);
}

// ---------------------------------------------------------------------------
// Kernel 0a: NCHW fp32 -> halo-padded NHWC bf16 (unchanged from prev round).
// ---------------------------------------------------------------------------
__global__ __launch_bounds__(256) void nchw2nhwc_pad(const float* __restrict__ x,
                                                     u16* __restrict__ xp) {
    __shared__ __align__(16) u16 T[64][264];
    const int tid = threadIdx.x;
    const int b   = blockIdx.x;
    const int n   = b >> 6;
    const int row = b & 63;
    const int g16 = tid >> 4;
    const int pxq = tid & 15;

    const float* src = x + ((size_t)n * 256 + g16 * 16) * 4096 + row * 64 + pxq * 4;
    float4 v[4][4];
#pragma unroll
    for (int u = 0; u < 4; ++u)
#pragma unroll
        for (int i = 0; i < 4; ++i)
            v[u][i] = *(const float4*)(src + (size_t)(u * 4 + i) * 4096);

#pragma unroll
    for (int u = 0; u < 4; ++u) {
        const int ic = g16 * 16 + u * 4;
#pragma unroll
        for (int e = 0; e < 4; ++e) {
            const int px = pxq * 4 + e;
            const u32 lo = ((u32)f2bf(COMP(v[u][1], e)) << 16) | f2bf(COMP(v[u][0], e));
            const u32 hi = ((u32)f2bf(COMP(v[u][3], e)) << 16) | f2bf(COMP(v[u][2], e));
            *(uint2*)&T[px][ic] = make_uint2(lo, hi);
        }
    }
    __syncthreads();

    const int c = tid & 31, p0 = tid >> 5;
    u16* dstN = xp + ((size_t)n * 4356 + (size_t)(row + 1) * 66 + 1) * 256 + c * 8;
#pragma unroll
    for (int pp = 0; pp < 8; ++pp) {
        const int px = pp * 8 + p0;
        *(uint4*)(dstN + (size_t)px * 256) = *(const uint4*)&T[px][c * 8];
    }

    u16* hrow = xp + ((size_t)n * 4356 + (size_t)(row + 1) * 66) * 256;
    if (tid < 64) {
        const int wp = (tid >> 5) ? 65 : 0;
        uint4 zz = {0u, 0u, 0u, 0u};
        *(uint4*)(hrow + (size_t)wp * 256 + (tid & 31) * 8) = zz;
    }
    if (row == 0) {
        u16* tb = xp + (size_t)n * 4356 * 256;
        uint4 zz = {0u, 0u, 0u, 0u};
        for (int i = tid; i < 2112; i += 256) *(uint4*)(tb + (size_t)i * 8) = zz;
    }
    if (row == 63) {
        u16* bb = xp + ((size_t)n * 4356 + 65 * 66) * 256;
        uint4 zz = {0u, 0u, 0u, 0u};
        for (int i = tid; i < 2112; i += 256) *(uint4*)(bb + (size_t)i * 8) = zz;
    }
}

// ---------------------------------------------------------------------------
// Kernel 0b: hypernet weight generation, LDS-resident (unchanged).
// ---------------------------------------------------------------------------
__global__ __launch_bounds__(256) void wgen(const float* __restrict__ z,
                                            const float* __restrict__ W1,
                                            const float* __restrict__ B1,
                                            const float* __restrict__ W2,
                                            const float* __restrict__ B2,
                                            u16* __restrict__ wb) {
    __shared__ float zl[64][65];
    __shared__ float w1s[4096];
    __shared__ float aS[64][65];
    __shared__ float w2s[9216];

    const int tid = threadIdx.x;
    const int b   = blockIdx.x >> 2;
    const int lc  = blockIdx.x & 3;
    const int l   = tid & 63;
    const int g   = tid >> 6;

    const float* zg  = z  + (size_t)lc * 4096;
    const float* w1g = W1 + (size_t)b * 4096;
    const float* w2g = W2 + (size_t)b * 9216;
#pragma unroll
    for (int k = 0; k < 4; ++k) {
        const int i4 = tid + k * 256;
        const float4 v = *(const float4*)(zg + (size_t)i4 * 4);
        const int lr = i4 >> 4, nr = (i4 * 4) & 63;
        zl[lr][nr] = v.x; zl[lr][nr + 1] = v.y; zl[lr][nr + 2] = v.z; zl[lr][nr + 3] = v.w;
        *(float4*)(w1s + (size_t)i4 * 4) = *(const float4*)(w1g + (size_t)i4 * 4);
    }
#pragma unroll
    for (int k = 0; k < 9; ++k) {
        const int i4 = tid + k * 256;
        *(float4*)(w2s + (size_t)i4 * 4) = *(const float4*)(w2g + (size_t)i4 * 4);
    }
    __syncthreads();

    {
        float acc[16];
#pragma unroll
        for (int j = 0; j < 16; ++j) acc[j] = B1[b * 64 + g * 16 + j];
#pragma unroll
        for (int nb = 0; nb < 16; ++nb) {
            float zv0 = zl[l][nb * 4 + 0];
            float zv1 = zl[l][nb * 4 + 1];
            float zv2 = zl[l][nb * 4 + 2];
            float zv3 = zl[l][nb * 4 + 3];
#pragma unroll
            for (int j = 0; j < 16; ++j) {
                const float4 w = *(const float4*)(w1s + (g * 16 + j) * 64 + nb * 4);
                acc[j] += w.x * zv0 + w.y * zv1 + w.z * zv2 + w.w * zv3;
            }
        }
#pragma unroll
        for (int j = 0; j < 16; ++j) aS[l][g * 16 + j] = acc[j];
    }
    __syncthreads();

    float acc2[36];
#pragma unroll
    for (int t = 0; t < 36; ++t) acc2[t] = B2[b * 144 + g * 36 + t];
#pragma unroll
    for (int db = 0; db < 16; ++db) {
        float av0 = aS[l][db * 4 + 0];
        float av1 = aS[l][db * 4 + 1];
        float av2 = aS[l][db * 4 + 2];
        float av3 = aS[l][db * 4 + 3];
#pragma unroll
        for (int t = 0; t < 36; ++t) {
            const float4 w = *(const float4*)(w2s + (g * 36 + t) * 64 + db * 4);
            acc2[t] += w.x * av0 + w.y * av1 + w.z * av2 + w.w * av3;
        }
    }

    const int lg = lc * 64 + l;
    const int ob = lg >> 4, ib = lg & 15;
#pragma unroll
    for (int t = 0; t < 36; ++t) {
        const int b2 = 4 * g + t / 9;
        const int tap = t % 9;
        wb[(size_t)(ob * 16 + b2) * 2304 + tap * 256 + ib * 16 + b] = f2bf(acc2[t]);
    }
}

// ---------------------------------------------------------------------------
// Kernel 1 REWRITE: phase-split pipelined implicit-GEMM conv (T3+T4+T5+T2).
// BM=256 (all oc) x BN=256 px x BK=32; 8 waves (2M x 4N); per-wave 128x64 out
// (acc[8][4] f32x4). 4-deep circular LDS buffer (4 x (16KB A + 16KB B) = 128KB);
// loads for tile t issued 3 tiles ahead -> steady-state wait is vmcnt(8),
// NEVER a full drain. One raw s_barrier per tile, asm-fenced both sides.
// LDS layout: 128B physical rows = 2 logical rows interleaved at 16B slots,
// phys_slot = (((row&1)<<2)|slot4) ^ ((row>>1)&7)  [involution, both sides]:
// gld16 stages linearly with pre-swizzled global source; ds_read_b128 is
// 2-way (free) on banks. setprio(1) around each 16-MFMA cluster.
// ---------------------------------------------------------------------------
__global__ __launch_bounds__(512, 2) void conv_mfma(const u16* __restrict__ xp,
                                                    const u16* __restrict__ wb,
                                                    float* __restrict__ out) {
    __shared__ __align__(16) u16 As[4][8192];   // 4 slots x 16 KB  [prow][slot]
    __shared__ __align__(16) u16 Bs[4][8192];   // 4 slots x 16 KB

    const int tid  = threadIdx.x;
    const int b0   = blockIdx.x;
    const int bid  = (b0 & 7) * 64 + (b0 >> 3);   // XCD-chunked, 512 % 8 == 0
    const int n    = bid >> 4;                    // image
    const int pimg = (bid & 15) << 8;             // 256 px = 4 image rows
    const int lane = tid & 63;
    const int wave = tid >> 6;
    const int wm = wave >> 2;                     // 0..1 (oc half)
    const int wn = wave & 3;                      // 0..3 (px quarter)
    const int lr = lane & 15, lq = lane >> 4;

    // ---- staging constants: thread -> (prow-in-round, phys slot) ----
    const int prw = tid >> 3;                     // 0..63
    const int psl = tid & 7;
    const int sl  = psl ^ (prw & 7);              // logical (parity<<2)|slot4
    const int s4o = (sl & 3) * 8;                 // ch offset within 32-k window
    const int par = sl >> 2;                      // row parity
    const int ocA0 = (prw)      * 2 + par;        // A round 0 row
    const int ocA1 = (64 + prw) * 2 + par;        // A round 1 row
    const u16* aG0 = wb + (size_t)ocA0 * 2304 + s4o;
    const u16* aG1 = wb + (size_t)ocA1 * 2304 + s4o;
    const int pxB0 = (prw)      * 2 + par;
    const int pxB1 = (64 + prw) * 2 + par;
    const int prow0 = (bid & 15) * 4;             // first image row of tile
    const int pb0 = (prow0 + (pxB0 >> 6) + 1) * 66 + (pxB0 & 63) + 1;
    const int pb1 = (prow0 + (pxB1 >> 6) + 1) * 66 + (pxB1 & 63) + 1;
    const u16* xpN = xp + (size_t)n * 4356 * 256 + s4o;
    const int ldst = wave * 512;                  // u16 offset of wave's 1KB seg

    f32x4 acc[8][4];
    const f32x4 z4 = {0.f, 0.f, 0.f, 0.f};
#pragma unroll
    for (int i = 0; i < 8; ++i)
#pragma unroll
        for (int j = 0; j < 4; ++j) acc[i][j] = z4;

    // stage tile t into slot t&3 (4 gld16/thread: A r0, A r1, B r0, B r1)
    auto stage = [&](int t) {
        const int s = t & 3;
        const int tap = t >> 3, icb = t & 7;
        const int t3 = tap / 3;
        const int dh = t3 - 1, dw = tap - t3 * 3 - 1;
        const int ko = tap * 256 + icb * 32;
        const int bo = (dh * 66 + dw) * 256 + icb * 32;
        u16* as_ = &As[s][ldst];
        u16* bs_ = &Bs[s][ldst];
        gld16(aG0 + ko, as_);
        gld16(aG1 + ko, as_ + 4096);
        gld16(xpN + (pb0 * 256 + bo), bs_);
        gld16(xpN + (pb1 * 256 + bo), bs_ + 4096);
    };

    auto compute = [&](int t) {
        const int s = t & 3;
        const u16* Ab = &As[s][0];
        const u16* Bb = &Bs[s][0];
        short8 bfr[4];
#pragma unroll
        for (int j = 0; j < 4; ++j) {
            const int px = wn * 64 + j * 16 + lr;
            const int pr = px >> 1;
            const int ps = (((px & 1) << 2) | lq) ^ (pr & 7);
            bfr[j] = *(const short8*)(Bb + pr * 64 + ps * 8);
        }
#pragma unroll
        for (int mh = 0; mh < 2; ++mh) {
            short8 afr[4];
#pragma unroll
            for (int i = 0; i < 4; ++i) {
                const int oc = wm * 128 + mh * 64 + i * 16 + lr;
                const int pr = oc >> 1;
                const int ps = (((oc & 1) << 2) | lq) ^ (pr & 7);
                afr[i] = *(const short8*)(Ab + pr * 64 + ps * 8);
            }
            __builtin_amdgcn_s_setprio(1);
#pragma unroll
            for (int i = 0; i < 4; ++i)
#pragma unroll
                for (int j = 0; j < 4; ++j)
                    acc[mh * 4 + i][j] = __builtin_amdgcn_mfma_f32_16x16x32_bf16(
                        afr[i], bfr[j], acc[mh * 4 + i][j], 0, 0, 0);
            __builtin_amdgcn_s_setprio(0);
        }
    };

    // prologue: 3 tiles in flight
    stage(0); stage(1); stage(2);

#pragma unroll 1
    for (int t = 0; t < 69; ++t) {
        asm volatile("s_waitcnt vmcnt(8)" ::: "memory");  // own tile-t loads landed
        __builtin_amdgcn_s_barrier();                     // all waves' landed
        asm volatile("" ::: "memory");
        compute(t);
        stage(t + 3);
    }
    // epilogue tiles 69..71 (no more issues; counted waits shrink)
    asm volatile("s_waitcnt vmcnt(8)" ::: "memory");
    __builtin_amdgcn_s_barrier();
    asm volatile("" ::: "memory");
    compute(69);
    asm volatile("s_waitcnt vmcnt(4)" ::: "memory");
    __builtin_amdgcn_s_barrier();
    asm volatile("" ::: "memory");
    compute(70);
    asm volatile("s_waitcnt vmcnt(0)" ::: "memory");
    __builtin_amdgcn_s_barrier();
    asm volatile("" ::: "memory");
    compute(71);

    // epilogue: C/D col=lane&15 (px), row=lq*4+reg (oc)
    const size_t outn = (size_t)n * 256 * 4096;
#pragma unroll
    for (int mi = 0; mi < 8; ++mi) {
        const int ocb = wm * 128 + mi * 16 + lq * 4;
#pragma unroll
        for (int j = 0; j < 4; ++j) {
            const int po = pimg + wn * 64 + j * 16 + lr;
            float* op = out + outn + (size_t)ocb * 4096 + po;
#pragma unroll
            for (int r = 0; r < 4; ++r) op[(size_t)r * 4096] = acc[mi][j][r];
        }
    }
}

extern "C" void kernel_launch(void* const* d_in, const int* in_sizes, int n_in,
                              void* d_out, int out_size, void* d_ws, size_t ws_size,
                              hipStream_t stream) {
    const float* x  = (const float*)d_in[0];
    const float* z  = (const float*)d_in[1];
    const float* W1 = (const float*)d_in[2];
    const float* B1 = (const float*)d_in[3];
    const float* W2 = (const float*)d_in[4];
    const float* B2 = (const float*)d_in[5];
    float* out = (float*)d_out;

    u16* xp = (u16*)d_ws;
    u16* wb = xp + (size_t)32 * 4356 * 256;
    const size_t need = ((size_t)32 * 4356 * 256 + (size_t)256 * 2304) * 2;
    if (ws_size < need) return;

    nchw2nhwc_pad<<<dim3(2048), dim3(256), 0, stream>>>(x, xp);
    wgen<<<dim3(64), dim3(256), 0, stream>>>(z, W1, B1, W2, B2, wb);
    conv_mfma<<<dim3(512), dim3(512), 0, stream>>>(xp, wb, out);
}